// Round 1
// baseline (18240.263 us; speedup 1.0000x reference)
//
#include <hip/hip_runtime.h>
#include <cstdint>
#include <cstddef>

// Decoder (LFADS-like): B=512, T=200. Precomposed weights:
//   W'  = com_W @ gen_K[:32]    (co_mean folded into generator input GEMM)
//   W'' = fac_Wn @ con_K[128:]  (factor path folded into controller input GEMM;
//                                fac_Wn columns appended -> facs output for free)
// Per step: 4 dependent bf16-MFMA GEMM stages, graph of 801 kernels.

#define B_   512
#define T_   200
#define CI_  128
#define EXT_ 8
#define GEN_ 800
#define CON_ 400
#define CO_  32
#define FAC_ 128

typedef __attribute__((ext_vector_type(8))) short short8;
typedef __attribute__((ext_vector_type(4))) float f32x4;

__device__ __forceinline__ unsigned short f2bf(float f) {
  unsigned int u = __float_as_uint(f);
  u += 0x7FFFu + ((u >> 16) & 1u);   // RNE
  return (unsigned short)(u >> 16);
}
__device__ __forceinline__ float sigm(float x) { return 1.0f / (1.0f + __expf(-x)); }

// ---------------- setup kernels ----------------

__global__ void k_facnorm(const float* __restrict__ facW, float* __restrict__ facWn) {
  int j = blockIdx.x;            // 0..127 (column)
  int l = threadIdx.x;           // 64 threads = 1 wave
  float s = 0.f;
  for (int k = l; k < GEN_; k += 64) { float v = facW[(size_t)k*FAC_ + j]; s += v*v; }
  #pragma unroll
  for (int off = 32; off > 0; off >>= 1) s += __shfl_down(s, off, 64);
  float inv = 1.0f / sqrtf(__shfl(s, 0, 64));
  for (int k = l; k < GEN_; k += 64) facWn[(size_t)k*FAC_ + j] = facW[(size_t)k*FAC_ + j] * inv;
}

// tmp2[kp][n] = sum_j facWn[kp][j] * conK[128+j][n]   (kp<800, n<1200)
__global__ void k_w2(const float* __restrict__ facWn, const float* __restrict__ conK,
                     float* __restrict__ tmp2) {
  int n = blockIdx.x*256 + threadIdx.x; if (n >= 1200) return;
  int kp = blockIdx.y;
  const float* fr = facWn + (size_t)kp*FAC_;
  float s = 0.f;
  for (int j = 0; j < FAC_; ++j) s = fmaf(fr[j], conK[(size_t)(CI_+j)*1200 + n], s);
  tmp2[(size_t)kp*1200 + n] = s;
}

// tmp1[k][n] = sum_j comW[k][j] * genK[j][n]   (k<400, n<2400)
__global__ void k_w1(const float* __restrict__ comW, const float* __restrict__ genK,
                     float* __restrict__ tmp1) {
  int n = blockIdx.x*256 + threadIdx.x; if (n >= 2400) return;
  int k = blockIdx.y;
  const float* cr = comW + (size_t)k*CO_;
  float s = 0.f;
  for (int j = 0; j < CO_; ++j) s = fmaf(cr[j], genK[(size_t)j*2400 + n], s);
  tmp1[(size_t)k*2400 + n] = s;
}

__global__ void k_init(const float* __restrict__ conh0, const float* __restrict__ geninit,
                       const float* __restrict__ conb, const float* __restrict__ genb,
                       const float* __restrict__ comb, const float* __restrict__ genK,
                       float* __restrict__ bczr, float* __restrict__ bgzr,
                       float* __restrict__ conh, unsigned short* __restrict__ agzr,
                       float* __restrict__ genh, unsigned short* __restrict__ genhb,
                       unsigned short* __restrict__ achh) {
  const long R0=1344, R1=2432, R2=(long)B_*CON_, R3=(long)B_*CON_,
             R4=(long)B_*GEN_, R5=(long)B_*GEN_, R6=(long)B_*416;
  const long total = R0+R1+R2+R3+R4+R5+R6;
  for (long idx = blockIdx.x*(long)blockDim.x + threadIdx.x; idx < total;
       idx += (long)gridDim.x*blockDim.x) {
    long i = idx;
    if (i < R0) { bczr[i] = (i < 1200) ? conb[i] : 0.f; continue; }
    i -= R0;
    if (i < R1) {
      float s = 0.f;
      if (i < 2400) { s = genb[i]; for (int j=0;j<32;++j) s = fmaf(comb[j], genK[(size_t)j*2400 + i], s); }
      bgzr[i] = s; continue;
    }
    i -= R1;
    if (i < R2) { conh[i] = conh0[i % CON_]; continue; }
    i -= R2;
    if (i < R3) { agzr[i] = f2bf(conh0[i % CON_]); continue; }
    i -= R3;
    if (i < R4) { genh[i] = geninit[i]; continue; }
    i -= R4;
    if (i < R5) { genhb[i] = f2bf(geninit[i]); continue; }
    i -= R5;
    achh[i] = 0;
  }
}

// build transposed bf16 weights: dst[n][k] = fetch(k, n)
struct BTArgs {
  int mode, K;
  const float* conK; const float* conR; const float* genK; const float* genR;
  const float* facWn; const float* tmp1; const float* tmp2;
  unsigned short* dst;
};

__device__ __forceinline__ float bt_fetch(const BTArgs& a, int k, int n) {
  switch (a.mode) {
    case 0: // W_czr^T: K=1344 (ci128|gen800|con416), N=1344 (z400|r400|xh400|fac128|pad)
      if (n < 1200) {
        if (k < 128)  return a.conK[(size_t)k*1200 + n];
        if (k < 928)  return a.tmp2[(size_t)(k-128)*1200 + n];
        if (k < 1328) return (n < 800) ? a.conR[(size_t)(k-928)*1200 + n] : 0.f;
        return 0.f;
      }
      if (n < 1328) return (k >= 128 && k < 928) ? a.facWn[(size_t)(k-128)*FAC_ + (n-1200)] : 0.f;
      return 0.f;
    case 1: // W_chh^T: con_R[:,800:1200]
      return (k < 400 && n < 400) ? a.conR[(size_t)k*1200 + 800 + n] : 0.f;
    case 2: // W_gzr^T: K=1216 (conh400|ext8|pad8|genh800), N=2432 (z800|r800|xh800|pad)
      if (n >= 2400) return 0.f;
      if (k < 400)  return a.tmp1[(size_t)k*2400 + n];
      if (k < 408)  return a.genK[(size_t)(32 + k - 400)*2400 + n];
      if (k < 416)  return 0.f;
      if (k < 1216) return (n < 1600) ? a.genR[(size_t)(k-416)*2400 + n] : 0.f;
      return 0.f;
    case 3: // W_ghh^T: gen_R[:,1600:2400]
      return (n < 800 && k < 800) ? a.genR[(size_t)k*2400 + 1600 + n] : 0.f;
    default: // fac_Wn^T [128][800]
      return (k < 800 && n < 128) ? a.facWn[(size_t)k*FAC_ + n] : 0.f;
  }
}

__global__ __launch_bounds__(256) void k_buildT(BTArgs a) {
  __shared__ float tile[64][65];
  int k0 = blockIdx.x*64, n0 = blockIdx.y*64;
  int tid = threadIdx.x;
  int rr = tid >> 2, cc = (tid & 3) * 16;
  #pragma unroll 4
  for (int i = 0; i < 16; ++i) tile[rr][cc+i] = bt_fetch(a, k0+rr, n0+cc+i);
  __syncthreads();
  int n = n0 + rr;
  if (k0 + cc < a.K) {    // K is a multiple of 16
    short8 v0, v1;
    #pragma unroll
    for (int i = 0; i < 8; ++i) v0[i] = (short)f2bf(tile[cc+i][rr]);
    #pragma unroll
    for (int i = 0; i < 8; ++i) v1[i] = (short)f2bf(tile[cc+8+i][rr]);
    *reinterpret_cast<short8*>(&a.dst[(size_t)n*a.K + k0 + cc])     = v0;
    *reinterpret_cast<short8*>(&a.dst[(size_t)n*a.K + k0 + cc + 8]) = v1;
  }
}

// ---------------- main GEMM stages ----------------

struct KArgs {
  const float* ci; const float* ext;
  const unsigned short* genhb;   // gen_h bf16 (state t-1)
  const unsigned short* agzr;    // con_h bf16
  const unsigned short* achh;    // r*h (con) bf16  [512x416]
  const unsigned short* aghh;    // r*h (gen) bf16  [512x800]
  const unsigned short* w;       // weight^T bf16 [NPAD x K]
  const float* bias;
  float* zcon; float* xhcon; float* zgen; float* xhgen;
  float* conh; float* genh;      // f32 masters
  unsigned short* achh_w; unsigned short* agzr_w; unsigned short* aghh_w; unsigned short* genhb_w;
  float* out;
  int t;
};

enum { S_CZR=0, S_CHH=1, S_GZR=2, S_GHH=3, S_FAC=4 };

template<int STAGE, int K>
__global__ __launch_bounds__(256)
void gemm_stage(KArgs a) {
  __shared__ unsigned short lA[64][40];   // pitch 40 -> 80B rows, 16B-aligned frags
  __shared__ unsigned short lB[64][40];
  const int tid  = threadIdx.x;
  const int lane = tid & 63;
  const int wid  = tid >> 6;
  const int wm = wid >> 1, wn = wid & 1;
  const int bm = blockIdx.x, bn = blockIdx.y;
  const int r = tid >> 2, q = tid & 3;
  const int brow = bm*64 + r;             // batch row (A side)
  const unsigned short* wp0 = a.w + (size_t)(bn*64 + r)*K;

  f32x4 acc[2][2];
  #pragma unroll
  for (int i=0;i<2;++i)
    #pragma unroll
    for (int j=0;j<2;++j) acc[i][j] = (f32x4){0.f,0.f,0.f,0.f};

  for (int kt = 0; kt < K/32; ++kt) {
    const int k0 = kt*32 + q*8;
    short8 av, bv;
    bv = *reinterpret_cast<const short8*>(wp0 + k0);
    if constexpr (STAGE == S_CZR) {
      if (k0 < 128) {
        const float* p = a.ci + ((size_t)brow*T_ + a.t)*CI_ + k0;
        float4 f0 = *reinterpret_cast<const float4*>(p);
        float4 f1 = *reinterpret_cast<const float4*>(p+4);
        av[0]=(short)f2bf(f0.x); av[1]=(short)f2bf(f0.y); av[2]=(short)f2bf(f0.z); av[3]=(short)f2bf(f0.w);
        av[4]=(short)f2bf(f1.x); av[5]=(short)f2bf(f1.y); av[6]=(short)f2bf(f1.z); av[7]=(short)f2bf(f1.w);
      } else if (k0 < 928) {
        av = *reinterpret_cast<const short8*>(a.genhb + (size_t)brow*GEN_ + (k0-128));
      } else if (k0 < 1328) {
        av = *reinterpret_cast<const short8*>(a.agzr + (size_t)brow*CON_ + (k0-928));
      } else {
        av = (short8){0,0,0,0,0,0,0,0};
      }
    } else if constexpr (STAGE == S_CHH) {
      av = *reinterpret_cast<const short8*>(a.achh + (size_t)brow*416 + k0);
    } else if constexpr (STAGE == S_GZR) {
      if (k0 < 400) {
        av = *reinterpret_cast<const short8*>(a.agzr + (size_t)brow*CON_ + k0);
      } else if (k0 < 408) {
        const float* p = a.ext + ((size_t)brow*T_ + a.t)*EXT_;
        float4 f0 = *reinterpret_cast<const float4*>(p);
        float4 f1 = *reinterpret_cast<const float4*>(p+4);
        av[0]=(short)f2bf(f0.x); av[1]=(short)f2bf(f0.y); av[2]=(short)f2bf(f0.z); av[3]=(short)f2bf(f0.w);
        av[4]=(short)f2bf(f1.x); av[5]=(short)f2bf(f1.y); av[6]=(short)f2bf(f1.z); av[7]=(short)f2bf(f1.w);
      } else if (k0 < 416) {
        av = (short8){0,0,0,0,0,0,0,0};
      } else {
        av = *reinterpret_cast<const short8*>(a.genhb + (size_t)brow*GEN_ + (k0-416));
      }
    } else if constexpr (STAGE == S_GHH) {
      av = *reinterpret_cast<const short8*>(a.aghh + (size_t)brow*GEN_ + k0);
    } else { // S_FAC
      av = *reinterpret_cast<const short8*>(a.genhb + (size_t)brow*GEN_ + k0);
    }
    __syncthreads();
    *reinterpret_cast<short8*>(&lA[r][q*8]) = av;
    *reinterpret_cast<short8*>(&lB[r][q*8]) = bv;
    __syncthreads();
    const int l15 = lane & 15, lk = (lane >> 4) * 8;
    short8 a0 = *reinterpret_cast<const short8*>(&lA[wm*32 +      l15][lk]);
    short8 a1 = *reinterpret_cast<const short8*>(&lA[wm*32 + 16 + l15][lk]);
    short8 b0 = *reinterpret_cast<const short8*>(&lB[wn*32 +      l15][lk]);
    short8 b1 = *reinterpret_cast<const short8*>(&lB[wn*32 + 16 + l15][lk]);
    acc[0][0] = __builtin_amdgcn_mfma_f32_16x16x32_bf16(a0, b0, acc[0][0], 0,0,0);
    acc[0][1] = __builtin_amdgcn_mfma_f32_16x16x32_bf16(a0, b1, acc[0][1], 0,0,0);
    acc[1][0] = __builtin_amdgcn_mfma_f32_16x16x32_bf16(a1, b0, acc[1][0], 0,0,0);
    acc[1][1] = __builtin_amdgcn_mfma_f32_16x16x32_bf16(a1, b1, acc[1][1], 0,0,0);
  }

  const int l15 = lane & 15, lrow = (lane >> 4) * 4;
  #pragma unroll
  for (int mi=0; mi<2; ++mi)
  #pragma unroll
  for (int ni=0; ni<2; ++ni)
  #pragma unroll
  for (int j=0; j<4; ++j) {
    int b = bm*64 + wm*32 + mi*16 + lrow + j;
    int c = bn*64 + wn*32 + ni*16 + l15;
    float v = acc[mi][ni][j];
    if constexpr (STAGE == S_CZR) {
      if (c < 400) {
        a.zcon[(size_t)b*CON_ + c] = sigm(v + a.bias[c]);
      } else if (c < 800) {
        int u = c - 400;
        a.achh_w[(size_t)b*416 + u] = f2bf(sigm(v + a.bias[c]) * a.conh[(size_t)b*CON_ + u]);
      } else if (c < 1200) {
        a.xhcon[(size_t)b*CON_ + (c-800)] = v + a.bias[c];
      } else if (c < 1328) {
        if (a.t > 0) a.out[((size_t)b*T_ + (a.t-1))*FAC_ + (c-1200)] = v;
      }
    } else if constexpr (STAGE == S_CHH) {
      if (c < 400) {
        float hh = tanhf(v + a.xhcon[(size_t)b*CON_ + c]);
        float z  = a.zcon[(size_t)b*CON_ + c];
        float h  = z * a.conh[(size_t)b*CON_ + c] + (1.f - z) * hh;
        h = fminf(fmaxf(h, -5.f), 5.f);
        a.conh[(size_t)b*CON_ + c] = h;
        a.agzr_w[(size_t)b*CON_ + c] = f2bf(h);
      }
    } else if constexpr (STAGE == S_GZR) {
      if (c < 800) {
        a.zgen[(size_t)b*GEN_ + c] = sigm(v + a.bias[c]);
      } else if (c < 1600) {
        int u = c - 800;
        a.aghh_w[(size_t)b*GEN_ + u] = f2bf(sigm(v + a.bias[c]) * a.genh[(size_t)b*GEN_ + u]);
      } else if (c < 2400) {
        a.xhgen[(size_t)b*GEN_ + (c-1600)] = v + a.bias[c];
      }
    } else if constexpr (STAGE == S_GHH) {
      if (c < 800) {
        float hh = tanhf(v + a.xhgen[(size_t)b*GEN_ + c]);
        float z  = a.zgen[(size_t)b*GEN_ + c];
        float h  = z * a.genh[(size_t)b*GEN_ + c] + (1.f - z) * hh;
        h = fminf(fmaxf(h, -5.f), 5.f);
        a.genh[(size_t)b*GEN_ + c] = h;
        a.genhb_w[(size_t)b*GEN_ + c] = f2bf(h);
      }
    } else { // S_FAC
      if (c < 128) a.out[((size_t)b*T_ + (T_-1))*FAC_ + c] = v;
    }
  }
}

// ---------------- host ----------------

extern "C" void kernel_launch(void* const* d_in, const int* in_sizes, int n_in,
                              void* d_out, int out_size, void* d_ws, size_t ws_size,
                              hipStream_t stream) {
  const float* ci      = (const float*)d_in[0];
  const float* ext     = (const float*)d_in[1];
  const float* geninit = (const float*)d_in[2];
  const float* conh0   = (const float*)d_in[3];
  const float* conK    = (const float*)d_in[4];
  const float* conR    = (const float*)d_in[5];
  const float* conb    = (const float*)d_in[6];
  const float* comW    = (const float*)d_in[7];
  const float* comb    = (const float*)d_in[8];
  const float* genK    = (const float*)d_in[11];
  const float* genR    = (const float*)d_in[12];
  const float* genb    = (const float*)d_in[13];
  const float* facW    = (const float*)d_in[14];
  float* out = (float*)d_out;

  char* ws = (char*)d_ws;
  size_t off = 0;
  auto alloc = [&](size_t bytes) -> void* {
    void* p = ws + off;
    off = (off + bytes + 255) & ~(size_t)255;
    return p;
  };
  unsigned short* wczr  = (unsigned short*)alloc(1344UL*1344*2);
  unsigned short* wchh  = (unsigned short*)alloc(448UL*416*2);
  unsigned short* wgzr  = (unsigned short*)alloc(2432UL*1216*2);
  unsigned short* wghh  = (unsigned short*)alloc(832UL*800*2);
  unsigned short* wfac  = (unsigned short*)alloc(128UL*800*2);
  float* facWn = (float*)alloc(800UL*128*4);
  float* tmp2  = (float*)alloc(800UL*1200*4);
  float* tmp1  = (float*)alloc(400UL*2400*4);
  float* bczr  = (float*)alloc(1344UL*4);
  float* bgzr  = (float*)alloc(2432UL*4);
  float* conh  = (float*)alloc((size_t)B_*CON_*4);
  float* genh  = (float*)alloc((size_t)B_*GEN_*4);
  unsigned short* genhb = (unsigned short*)alloc((size_t)B_*GEN_*2);
  unsigned short* agzr  = (unsigned short*)alloc((size_t)B_*CON_*2);
  unsigned short* achh  = (unsigned short*)alloc((size_t)B_*416*2);
  unsigned short* aghh  = (unsigned short*)alloc((size_t)B_*GEN_*2);
  float* zcon  = (float*)alloc((size_t)B_*CON_*4);
  float* xhcon = (float*)alloc((size_t)B_*CON_*4);
  float* zgen  = (float*)alloc((size_t)B_*GEN_*4);
  float* xhgen = (float*)alloc((size_t)B_*GEN_*4);
  (void)ws_size; (void)in_sizes; (void)n_in; (void)out_size;

  dim3 blk(256);
  k_facnorm<<<dim3(128), dim3(64), 0, stream>>>(facW, facWn);
  k_w2<<<dim3(5, 800), blk, 0, stream>>>(facWn, conK, tmp2);
  k_w1<<<dim3(10, 400), blk, 0, stream>>>(comW, genK, tmp1);
  k_init<<<dim3(2048), blk, 0, stream>>>(conh0, geninit, conb, genb, comb, genK,
                                         bczr, bgzr, conh, agzr, genh, genhb, achh);

  BTArgs bt;
  bt.conK = conK; bt.conR = conR; bt.genK = genK; bt.genR = genR;
  bt.facWn = facWn; bt.tmp1 = tmp1; bt.tmp2 = tmp2;
  bt.mode = 0; bt.K = 1344; bt.dst = wczr; k_buildT<<<dim3(21,21), blk, 0, stream>>>(bt);
  bt.mode = 1; bt.K = 416;  bt.dst = wchh; k_buildT<<<dim3(7,7),   blk, 0, stream>>>(bt);
  bt.mode = 2; bt.K = 1216; bt.dst = wgzr; k_buildT<<<dim3(19,38), blk, 0, stream>>>(bt);
  bt.mode = 3; bt.K = 800;  bt.dst = wghh; k_buildT<<<dim3(13,13), blk, 0, stream>>>(bt);
  bt.mode = 4; bt.K = 800;  bt.dst = wfac; k_buildT<<<dim3(13,2),  blk, 0, stream>>>(bt);

  KArgs ka;
  ka.ci = ci; ka.ext = ext;
  ka.genhb = genhb; ka.agzr = agzr; ka.achh = achh; ka.aghh = aghh;
  ka.zcon = zcon; ka.xhcon = xhcon; ka.zgen = zgen; ka.xhgen = xhgen;
  ka.conh = conh; ka.genh = genh;
  ka.achh_w = achh; ka.agzr_w = agzr; ka.aghh_w = aghh; ka.genhb_w = genhb;
  ka.out = out;

  for (int t = 0; t < T_; ++t) {
    ka.t = t;
    ka.w = wczr; ka.bias = bczr;
    gemm_stage<S_CZR, 1344><<<dim3(8,21), blk, 0, stream>>>(ka);
    ka.w = wchh;
    gemm_stage<S_CHH, 416><<<dim3(8,7), blk, 0, stream>>>(ka);
    ka.w = wgzr; ka.bias = bgzr;
    gemm_stage<S_GZR, 1216><<<dim3(8,38), blk, 0, stream>>>(ka);
    ka.w = wghh;
    gemm_stage<S_GHH, 800><<<dim3(8,13), blk, 0, stream>>>(ka);
  }
  ka.t = T_ - 1;
  ka.w = wfac; ka.bias = bczr;
  gemm_stage<S_FAC, 800><<<dim3(8,2), blk, 0, stream>>>(ka);
}